// Round 3
// baseline (281.827 us; speedup 1.0000x reference)
//
#include <hip/hip_runtime.h>

// out = softmax(q @ keys^T) @ keys, fused flash-style, round 3.
// r2's tr-read PV operand failed (uncertain HW semantics) -> replaced by
// MFMA-identity transpose: KT = mfma(K_chunk, I16) per 16x16 subtile, shared
// across the block in a KT LDS buffer. Score/softmax/PV dataflow = r1's
// hardware-proven mappings (no permutations, no inline asm). Double-buffered
// K staging (issue-early/write-late), 2 barriers/tile, 3 blocks/CU.

typedef _Float16 f16;
typedef f16 f16x8 __attribute__((ext_vector_type(8)));
typedef f16 f16x4 __attribute__((ext_vector_type(4)));
typedef float f32x4 __attribute__((ext_vector_type(4)));

#define D_DIM 256
#define KVB 32
#define NT 64
#define KPAD 264   // f16 per K row (256 + 8 pad) -> 528B rows, 16B-aligned
#define KTPAD 40   // f16 per KT row (32 keys + 8 pad) -> 80B rows, 16B-aligned

#define MF32(a, b, c) __builtin_amdgcn_mfma_f32_16x16x32_f16(a, b, c, 0, 0, 0)
#define MF16(a, b, c) __builtin_amdgcn_mfma_f32_16x16x16f16(a, b, c, 0, 0, 0)

__device__ __forceinline__ f16x8 cvt8(float4 a, float4 b) {
  f16x8 r;
  r[0] = (f16)a.x; r[1] = (f16)a.y; r[2] = (f16)a.z; r[3] = (f16)a.w;
  r[4] = (f16)b.x; r[5] = (f16)b.y; r[6] = (f16)b.z; r[7] = (f16)b.w;
  return r;
}

__global__ __launch_bounds__(256, 3)
void mtr_kernel(const float* __restrict__ keys,
                const float* __restrict__ query,
                float* __restrict__ out) {
  __shared__ f16 KB[2][KVB * KPAD];   // 33792 B (key-major, double-buffered)
  __shared__ f16 KT[D_DIM * KTPAD];   // 20480 B (d-major, single, per-tile)

  const int tid  = threadIdx.x;
  const int lane = tid & 63;
  const int wave = tid >> 6;   // 0..3
  const int g    = lane >> 4;  // 0..3
  const int qr   = lane & 15;

  const int nbase  = blockIdx.x * 64;
  const int b      = nbase >> 12;
  const int hwbase = nbase & 4095;

  // ---- q fragments, hi/lo fp16 split (q exact). Score B-layout:
  // lane holds q[row=qr][d = dt*32 + g*8 + j]
  f16x8 qh[8], ql[8];
  {
    const float* qb = query + ((size_t)b << 20) + hwbase + wave * 16 + qr;
    #pragma unroll
    for (int dt = 0; dt < 8; ++dt) {
      #pragma unroll
      for (int j = 0; j < 8; ++j) {
        int c = dt * 32 + g * 8 + j;
        float v = qb[(size_t)c << 12];
        f16 h = (f16)v;
        qh[dt][j] = h;
        ql[dt][j] = (f16)(v - (float)h);
      }
    }
  }

  f32x4 O[16];
  #pragma unroll
  for (int i = 0; i < 16; ++i) O[i] = (f32x4){0.f, 0.f, 0.f, 0.f};
  float m_run = -INFINITY, l_run = 0.f;

  // identity B-frag for the transpose mfma: I[k = g*4+i][col = qr]
  f16x4 ib;
  #pragma unroll
  for (int i = 0; i < 4; ++i) ib[i] = (f16)((g * 4 + i == qr) ? 1.0f : 0.0f);

  // staging: thread -> key = tid>>3, d-chunk (tid&7)*16 (+128 for 2nd half)
  const int s_key = tid >> 3;
  const int s_d0  = (tid & 7) * 16;
  const int s_i0  = s_key * KPAD + s_d0;

  f16x8 r0, r1, r2, r3;
  {
    const float* kp = keys + (size_t)s_key * D_DIM + s_d0;
    float4 u0 = ((const float4*)kp)[0], u1 = ((const float4*)kp)[1];
    float4 u2 = ((const float4*)kp)[2], u3 = ((const float4*)kp)[3];
    const float* kq = kp + 128;
    float4 w0 = ((const float4*)kq)[0], w1 = ((const float4*)kq)[1];
    float4 w2 = ((const float4*)kq)[2], w3 = ((const float4*)kq)[3];
    *(f16x8*)&KB[0][s_i0]           = cvt8(u0, u1);
    *(f16x8*)&KB[0][s_i0 + 8]       = cvt8(u2, u3);
    *(f16x8*)&KB[0][s_i0 + 128]     = cvt8(w0, w1);
    *(f16x8*)&KB[0][s_i0 + 128 + 8] = cvt8(w2, w3);
  }
  __syncthreads();

  const int dt0 = wave * 4;  // this wave's transpose dtiles

  for (int t = 0; t < NT; ++t) {
    const int cur = t & 1;
    const bool has_next = (t + 1) < NT;

    // ---- issue next-tile global loads early (hide HBM/L2 latency)
    if (has_next) {
      const float* kp = keys + (size_t)((t + 1) * KVB + s_key) * D_DIM + s_d0;
      float4 u0 = ((const float4*)kp)[0], u1 = ((const float4*)kp)[1];
      float4 u2 = ((const float4*)kp)[2], u3 = ((const float4*)kp)[3];
      const float* kq = kp + 128;
      float4 w0 = ((const float4*)kq)[0], w1 = ((const float4*)kq)[1];
      float4 w2 = ((const float4*)kq)[2], w3 = ((const float4*)kq)[3];
      r0 = cvt8(u0, u1); r1 = cvt8(u2, u3);
      r2 = cvt8(w0, w1); r3 = cvt8(w2, w3);
    }

    const f16* KC = &KB[cur][0];

    // ---- transpose this wave's 8 subtiles via mfma with identity:
    // C[lane g,qr][i] = K[kt*16 + g*4+i][dtile*16 + qr] -> KT[d][key]
    #pragma unroll
    for (int kt = 0; kt < 2; ++kt)
      #pragma unroll
      for (int dd = 0; dd < 4; ++dd) {
        int dtile = dt0 + dd;
        f16x4 av = *(const f16x4*)&KC[(kt * 16 + qr) * KPAD + dtile * 16 + g * 4];
        f32x4 c = MF16(av, ib, ((f32x4){0.f, 0.f, 0.f, 0.f}));
        f16x4 kv;
        kv[0] = (f16)c[0]; kv[1] = (f16)c[1]; kv[2] = (f16)c[2]; kv[3] = (f16)c[3];
        *(f16x4*)&KT[(dtile * 16 + qr) * KTPAD + kt * 16 + g * 4] = kv;
      }

    // ---- score: S^T = K·qh + K·ql (q exact via split), r1 mapping
    f32x4 st0 = (f32x4){0.f, 0.f, 0.f, 0.f};
    f32x4 st1 = (f32x4){0.f, 0.f, 0.f, 0.f};
    #pragma unroll
    for (int dt = 0; dt < 8; ++dt) {
      f16x8 a0 = *(const f16x8*)&KC[qr * KPAD + dt * 32 + g * 8];
      f16x8 a1 = *(const f16x8*)&KC[(16 + qr) * KPAD + dt * 32 + g * 8];
      st0 = MF32(a0, qh[dt], st0);
      st0 = MF32(a0, ql[dt], st0);
      st1 = MF32(a1, qh[dt], st1);
      st1 = MF32(a1, ql[dt], st1);
    }
    // lane holds S[q=qr][key kt*16 + g*4 + i]

    // ---- online softmax (row = qr)
    float tmax = st0[0];
    tmax = fmaxf(tmax, st0[1]); tmax = fmaxf(tmax, st0[2]); tmax = fmaxf(tmax, st0[3]);
    tmax = fmaxf(tmax, st1[0]); tmax = fmaxf(tmax, st1[1]);
    tmax = fmaxf(tmax, st1[2]); tmax = fmaxf(tmax, st1[3]);
    tmax = fmaxf(tmax, __shfl_xor(tmax, 16));
    tmax = fmaxf(tmax, __shfl_xor(tmax, 32));

    if (__any(tmax > m_run + 8.f)) {  // defer-max (T13)
      float m_new = fmaxf(m_run, tmax);
      float sc = __expf(m_run - m_new);
      l_run *= sc;
      m_run = m_new;
      float osc0 = __shfl(sc, g * 4 + 0);
      float osc1 = __shfl(sc, g * 4 + 1);
      float osc2 = __shfl(sc, g * 4 + 2);
      float osc3 = __shfl(sc, g * 4 + 3);
      #pragma unroll
      for (int dtile = 0; dtile < 16; ++dtile) {
        O[dtile][0] *= osc0; O[dtile][1] *= osc1;
        O[dtile][2] *= osc2; O[dtile][3] *= osc3;
      }
    }

    float ts = 0.f;
    f16x4 pa[2];
    #pragma unroll
    for (int i = 0; i < 4; ++i) {
      float e0 = __expf(st0[i] - m_run);
      float e1 = __expf(st1[i] - m_run);
      ts += e0 + e1;
      pa[0][i] = (f16)e0;
      pa[1][i] = (f16)e1;
    }
    ts += __shfl_xor(ts, 16);
    ts += __shfl_xor(ts, 32);
    l_run += ts;

    __syncthreads();  // KT complete (all waves)

    // ---- PV: O[q][d] += P @ K_tile, x16 pairs, B from KT (b64, bank-minimal)
    #pragma unroll
    for (int dtile = 0; dtile < 16; ++dtile) {
      f16x4 v0 = *(const f16x4*)&KT[(dtile * 16 + qr) * KTPAD + g * 4];
      f16x4 v1 = *(const f16x4*)&KT[(dtile * 16 + qr) * KTPAD + 16 + g * 4];
      O[dtile] = MF16(pa[0], v0, O[dtile]);
      O[dtile] = MF16(pa[1], v1, O[dtile]);
    }

    // ---- write next K tile into other buffer
    if (has_next) {
      const int nxt = cur ^ 1;
      *(f16x8*)&KB[nxt][s_i0]           = r0;
      *(f16x8*)&KB[nxt][s_i0 + 8]       = r1;
      *(f16x8*)&KB[nxt][s_i0 + 128]     = r2;
      *(f16x8*)&KB[nxt][s_i0 + 128 + 8] = r3;
    }
    __syncthreads();  // KB[nxt] ready; KT free for next tile
  }

  // ---- epilogue: normalize by row-sum, store NCHW (float4 over w)
  float n0 = 1.f / __shfl(l_run, g * 4 + 0);
  float n1 = 1.f / __shfl(l_run, g * 4 + 1);
  float n2 = 1.f / __shfl(l_run, g * 4 + 2);
  float n3 = 1.f / __shfl(l_run, g * 4 + 3);
  float* ob = out + ((size_t)b << 20) + hwbase + wave * 16 + g * 4;
  #pragma unroll
  for (int dtile = 0; dtile < 16; ++dtile) {
    int c = dtile * 16 + qr;
    float4 w4;
    w4.x = O[dtile][0] * n0;
    w4.y = O[dtile][1] * n1;
    w4.z = O[dtile][2] * n2;
    w4.w = O[dtile][3] * n3;
    *(float4*)(ob + ((size_t)c << 12)) = w4;
  }
}

extern "C" void kernel_launch(void* const* d_in, const int* in_sizes, int n_in,
                              void* d_out, int out_size, void* d_ws, size_t ws_size,
                              hipStream_t stream) {
  const float* keys  = (const float*)d_in[0];
  const float* query = (const float*)d_in[1];
  float* out = (float*)d_out;
  hipLaunchKernelGGL(mtr_kernel, dim3(512), dim3(256), 0, stream, keys, query, out);
}

// Round 4
// 163.226 us; speedup vs baseline: 1.7266x; 1.7266x over previous
//
#include <hip/hip_runtime.h>

// out = softmax(q @ keys^T) @ keys, fused flash-style, round 4.
// Pre-kernel converts keys -> fp16 and writes PER-TILE, PRE-SWIZZLED LDS
// images into d_ws:  [0,1MB): Kh images (key-major, chunk^=(key&7));
// [1MB,2MB): KT images (d-major pair-rows, slot ((d&1)*4|g)^((d>>1)&7)).
// Main kernel DMAs images via global_load_lds (linear), reads them with
// bank-2-way patterns, score x32 with key-permuted A-rows feeding an all-x32
// PV. 2-wave blocks, 32 q-rows/wave, dbuf, 1 barrier/tile.

typedef _Float16 f16;
typedef f16 f16x8 __attribute__((ext_vector_type(8)));
typedef float f32x4 __attribute__((ext_vector_type(4)));

#define NT 64
#define MF32(a, b, c) __builtin_amdgcn_mfma_f32_16x16x32_f16(a, b, c, 0, 0, 0)

__device__ __forceinline__ void gl_lds16(const f16* g, f16* l) {
  __builtin_amdgcn_global_load_lds(
      (const __attribute__((address_space(1))) void*)g,
      (__attribute__((address_space(3))) void*)l, 16, 0, 0);
}

// ---- pre-kernel: build swizzled per-tile images (grid 256 x 256) ----
__global__ void prep_kernel(const float* __restrict__ keys, f16* __restrict__ ws) {
  int i = blockIdx.x * 256 + threadIdx.x;  // 0..65535
  int t = i >> 10;
  {  // Kh image: key kk, chunk c (8 f16 of dims c*8..c*8+7)
    int kk = (i >> 5) & 31, c = i & 31;
    const float* src = keys + (((t << 5) + kk) << 8) + (c << 3);
    f16x8 v;
    #pragma unroll
    for (int e = 0; e < 8; ++e) v[e] = (f16)src[e];
    *(f16x8*)&ws[t * 8192 + kk * 256 + ((c ^ (kk & 7)) << 3)] = v;
  }
  {  // KT image: dim d, key-group g (keys g*8..g*8+7 at dim d)
    int d = (i >> 2) & 255, g = i & 3;
    const float* src = keys + (((t << 5) + (g << 3)) << 8) + d;
    f16x8 v;
    #pragma unroll
    for (int j = 0; j < 8; ++j) v[j] = (f16)src[j << 8];
    *(f16x8*)&ws[524288 + t * 8192 + (d >> 1) * 64 +
                 (((((d & 1) << 2) | g) ^ ((d >> 1) & 7)) << 3)] = v;
  }
}

__global__ __launch_bounds__(128, 1)
void mtr_kernel(const f16* __restrict__ ws,
                const float* __restrict__ query,
                float* __restrict__ out) {
  __shared__ f16 KB[2][8192];   // 32 KB: Kh images (dbuf)
  __shared__ f16 KT[2][8192];   // 32 KB: KT images (dbuf)

  const int tid  = threadIdx.x;
  const int lane = tid & 63;
  const int wave = tid >> 6;   // 0..1
  const int g    = lane >> 4;  // 0..3
  const int qr   = lane & 15;

  const int nbase  = blockIdx.x * 64;
  const int b      = nbase >> 12;
  const int hwbase = nbase & 4095;

  // ---- q fragments, 2 groups of 16 rows, hi/lo fp16 split (q exact).
  // B-layout: lane holds q[row=qr][d = dt*32 + g*8 + j]
  f16x8 qh0[8], ql0[8], qh1[8], ql1[8];
  #pragma unroll
  for (int grp = 0; grp < 2; ++grp) {
    const float* qb = query + ((size_t)b << 20) + hwbase + wave * 32 + grp * 16 + qr;
    #pragma unroll
    for (int dt = 0; dt < 8; ++dt)
      #pragma unroll
      for (int j = 0; j < 8; ++j) {
        int c = dt * 32 + g * 8 + j;
        float v = qb[(size_t)c << 12];
        f16 h = (f16)v;
        if (grp == 0) { qh0[dt][j] = h; ql0[dt][j] = (f16)(v - (float)h); }
        else          { qh1[dt][j] = h; ql1[dt][j] = (f16)(v - (float)h); }
      }
  }

  f32x4 O0[16], O1[16];
  #pragma unroll
  for (int i = 0; i < 16; ++i) {
    O0[i] = (f32x4){0.f, 0.f, 0.f, 0.f};
    O1[i] = (f32x4){0.f, 0.f, 0.f, 0.f};
  }
  float m0 = -INFINITY, l0 = 0.f, m1 = -INFINITY, l1 = 0.f;

  // score A-rows: key-permuted phys key = 8*(qr>>2) + 4*kt + (qr&3)
  const int pk0 = ((qr >> 2) << 3) + (qr & 3);
  const int rb0 = pk0 << 8;          // f16 offset of row pk0 (512B rows)
  const int rb1 = rb0 + 1024;        // pk0+4
  const int x0  = qr & 3;            // pk0 & 7
  const int x1  = x0 | 4;            // (pk0+4) & 7
  // PV read row-base (f16 units) within each dtile's 1KB
  const int rbT = ((qr >> 1) << 6) + (((((qr & 1) << 2) | g) ^ ((qr >> 1) & 7)) << 3);

  // ---- DMA helper data: wave0 -> KB, wave1 -> KT (16 x 1KB each)
  const f16* wsrc = ws + (wave ? 524288 : 0) + lane * 8;

  // prologue: stage tile 0
  {
    f16* dst = wave ? &KT[0][0] : &KB[0][0];
    const f16* s = wsrc;  // t = 0
    #pragma unroll
    for (int i = 0; i < 16; ++i) gl_lds16(s + i * 512, dst + i * 512);
  }
  __syncthreads();

  for (int t = 0; t < NT; ++t) {
    const int cur = t & 1;

    // ---- issue next-tile DMA into other buffer
    if (t + 1 < NT) {
      f16* dst = wave ? &KT[cur ^ 1][0] : &KB[cur ^ 1][0];
      const f16* s = wsrc + (t + 1) * 8192;
      #pragma unroll
      for (int i = 0; i < 16; ++i) gl_lds16(s + i * 512, dst + i * 512);
    }

    // ---- score: S^T[key'][q] for both q-groups (key-permuted A-rows)
    const f16* KBc = &KB[cur][0];
    f32x4 s00 = (f32x4){0.f,0.f,0.f,0.f}, s10 = (f32x4){0.f,0.f,0.f,0.f};
    f32x4 s01 = (f32x4){0.f,0.f,0.f,0.f}, s11 = (f32x4){0.f,0.f,0.f,0.f};
    #pragma unroll
    for (int dt = 0; dt < 8; ++dt) {
      int c = (dt << 2) + g;
      f16x8 a0 = *(const f16x8*)&KBc[rb0 + ((c ^ x0) << 3)];
      f16x8 a1 = *(const f16x8*)&KBc[rb1 + ((c ^ x1) << 3)];
      s00 = MF32(a0, qh0[dt], s00); s00 = MF32(a0, ql0[dt], s00);
      s10 = MF32(a1, qh0[dt], s10); s10 = MF32(a1, ql0[dt], s10);
      s01 = MF32(a0, qh1[dt], s01); s01 = MF32(a0, ql1[dt], s01);
      s11 = MF32(a1, qh1[dt], s11); s11 = MF32(a1, ql1[dt], s11);
    }
    // lane holds S[q=qr][key 8g+i] (s0*) and 8g+4+i (s1*) per group

    // ---- online softmax per group; build x32 PV A-frags
    f16x8 pa0, pa1;
    #pragma unroll
    for (int grp = 0; grp < 2; ++grp) {
      f32x4& sa = grp ? s01 : s00;
      f32x4& sb = grp ? s11 : s10;
      float& mr = grp ? m1 : m0;
      float& lr = grp ? l1 : l0;
      float tmax = fmaxf(fmaxf(fmaxf(sa[0], sa[1]), fmaxf(sa[2], sa[3])),
                         fmaxf(fmaxf(sb[0], sb[1]), fmaxf(sb[2], sb[3])));
      tmax = fmaxf(tmax, __shfl_xor(tmax, 16));
      tmax = fmaxf(tmax, __shfl_xor(tmax, 32));
      if (__any(tmax > mr + 8.f)) {  // defer-max (T13)
        float m_new = fmaxf(mr, tmax);
        float sc = __expf(mr - m_new);
        lr *= sc;
        mr = m_new;
        float osc0 = __shfl(sc, g * 4 + 0);
        float osc1 = __shfl(sc, g * 4 + 1);
        float osc2 = __shfl(sc, g * 4 + 2);
        float osc3 = __shfl(sc, g * 4 + 3);
        f32x4* O = grp ? O1 : O0;
        #pragma unroll
        for (int dtile = 0; dtile < 16; ++dtile) {
          O[dtile][0] *= osc0; O[dtile][1] *= osc1;
          O[dtile][2] *= osc2; O[dtile][3] *= osc3;
        }
      }
      float ts = 0.f;
      f16x8& pa = grp ? pa1 : pa0;
      #pragma unroll
      for (int i = 0; i < 4; ++i) {
        float e0 = __expf(sa[i] - mr);
        float e1 = __expf(sb[i] - mr);
        ts += e0 + e1;
        pa[i] = (f16)e0;
        pa[4 + i] = (f16)e1;
      }
      ts += __shfl_xor(ts, 16);
      ts += __shfl_xor(ts, 32);
      lr += ts;
    }

    // ---- PV: all-x32, B-frags = KT image b128 at compile-time strides
    const f16* KTc = &KT[cur][0];
    #pragma unroll
    for (int dtile = 0; dtile < 16; ++dtile) {
      f16x8 vb = *(const f16x8*)&KTc[dtile * 512 + rbT];
      O0[dtile] = MF32(pa0, vb, O0[dtile]);
      O1[dtile] = MF32(pa1, vb, O1[dtile]);
    }

    __syncthreads();  // drains this wave's DMA (vmcnt0) + orders buffers
  }

  // ---- epilogue: normalize, store NCHW (float4 over w)
  #pragma unroll
  for (int grp = 0; grp < 2; ++grp) {
    float lr = grp ? l1 : l0;
    float n0 = 1.f / __shfl(lr, g * 4 + 0);
    float n1 = 1.f / __shfl(lr, g * 4 + 1);
    float n2 = 1.f / __shfl(lr, g * 4 + 2);
    float n3 = 1.f / __shfl(lr, g * 4 + 3);
    f32x4* O = grp ? O1 : O0;
    float* ob = out + ((size_t)b << 20) + hwbase + wave * 32 + grp * 16 + g * 4;
    #pragma unroll
    for (int dtile = 0; dtile < 16; ++dtile) {
      int c = dtile * 16 + qr;
      float4 w4;
      w4.x = O[dtile][0] * n0;
      w4.y = O[dtile][1] * n1;
      w4.z = O[dtile][2] * n2;
      w4.w = O[dtile][3] * n3;
      *(float4*)(ob + ((size_t)c << 12)) = w4;
    }
  }
}

extern "C" void kernel_launch(void* const* d_in, const int* in_sizes, int n_in,
                              void* d_out, int out_size, void* d_ws, size_t ws_size,
                              hipStream_t stream) {
  const float* keys  = (const float*)d_in[0];
  const float* query = (const float*)d_in[1];
  float* out = (float*)d_out;
  f16* ws = (f16*)d_ws;
  hipLaunchKernelGGL(prep_kernel, dim3(256), dim3(256), 0, stream, keys, ws);
  hipLaunchKernelGGL(mtr_kernel, dim3(512), dim3(128), 0, stream, ws, query, out);
}

// Round 5
// 133.347 us; speedup vs baseline: 2.1135x; 1.2241x over previous
//
#include <hip/hip_runtime.h>

// out = softmax(q @ keys^T) @ keys, fused flash-style, round 5.
// Same dataflow as r4 (pre-swizzled Kh/KT images in d_ws, global_load_lds
// staging, key-permuted x32 score + all-x32 PV, defer-max online softmax).
// Structural change: 256-thread blocks (4 waves x 16 q-rows), grid 512,
// 2 blocks/CU -> 2 waves/SIMD (was 1) for latency hiding.

typedef _Float16 f16;
typedef f16 f16x8 __attribute__((ext_vector_type(8)));
typedef float f32x4 __attribute__((ext_vector_type(4)));

#define NT 64
#define MF32(a, b, c) __builtin_amdgcn_mfma_f32_16x16x32_f16(a, b, c, 0, 0, 0)

__device__ __forceinline__ void gl_lds16(const f16* g, f16* l) {
  __builtin_amdgcn_global_load_lds(
      (const __attribute__((address_space(1))) void*)g,
      (__attribute__((address_space(3))) void*)l, 16, 0, 0);
}

// ---- pre-kernel: build swizzled per-tile images (grid 256 x 256) ----
__global__ void prep_kernel(const float* __restrict__ keys, f16* __restrict__ ws) {
  int i = blockIdx.x * 256 + threadIdx.x;  // 0..65535
  int t = i >> 10;
  {  // Kh image: key kk, chunk c (8 f16 of dims c*8..c*8+7), chunk^=(kk&7)
    int kk = (i >> 5) & 31, c = i & 31;
    const float* src = keys + (((t << 5) + kk) << 8) + (c << 3);
    f16x8 v;
    #pragma unroll
    for (int e = 0; e < 8; ++e) v[e] = (f16)src[e];
    *(f16x8*)&ws[t * 8192 + kk * 256 + ((c ^ (kk & 7)) << 3)] = v;
  }
  {  // KT image: dim d, key-group g (keys g*8..g*8+7 at dim d), swizzled slot
    int d = (i >> 2) & 255, g = i & 3;
    const float* src = keys + (((t << 5) + (g << 3)) << 8) + d;
    f16x8 v;
    #pragma unroll
    for (int j = 0; j < 8; ++j) v[j] = (f16)src[j << 8];
    *(f16x8*)&ws[524288 + t * 8192 + (d >> 1) * 64 +
                 (((((d & 1) << 2) | g) ^ ((d >> 1) & 7)) << 3)] = v;
  }
}

__global__ __launch_bounds__(256, 2)
void mtr_kernel(const f16* __restrict__ ws,
                const float* __restrict__ query,
                float* __restrict__ out) {
  __shared__ f16 KB[2][8192];   // 32 KB: Kh images (dbuf)
  __shared__ f16 KT[2][8192];   // 32 KB: KT images (dbuf)

  const int tid  = threadIdx.x;
  const int lane = tid & 63;
  const int wave = tid >> 6;   // 0..3, owns q-rows [wave*16, wave*16+16)
  const int g    = lane >> 4;  // 0..3
  const int qr   = lane & 15;

  const int nbase  = blockIdx.x * 64;
  const int b      = nbase >> 12;
  const int hwbase = nbase & 4095;

  // ---- q fragments, hi/lo fp16 split (q exact). Score B-layout:
  // lane holds q[row=qr][d = dt*32 + g*8 + j]
  f16x8 qh[8], ql[8];
  {
    const float* qb = query + ((size_t)b << 20) + hwbase + wave * 16 + qr;
    #pragma unroll
    for (int dt = 0; dt < 8; ++dt)
      #pragma unroll
      for (int j = 0; j < 8; ++j) {
        int c = dt * 32 + g * 8 + j;
        float v = qb[(size_t)c << 12];
        f16 h = (f16)v;
        qh[dt][j] = h;
        ql[dt][j] = (f16)(v - (float)h);
      }
  }

  f32x4 O[16];
  #pragma unroll
  for (int i = 0; i < 16; ++i) O[i] = (f32x4){0.f, 0.f, 0.f, 0.f};
  float m_run = -INFINITY, l_run = 0.f;

  // score A-rows: key-permuted phys key = 8*(qr>>2) + 4*kt + (qr&3)
  const int rb0 = (((qr >> 2) << 3) + (qr & 3)) << 8;  // row pk0 (512B rows)
  const int rb1 = rb0 + 1024;                          // pk0 + 4
  const int x0  = qr & 3;
  const int x1  = x0 | 4;
  // PV read row-base (f16 units) within each dtile's 1KB
  const int rbT = ((qr >> 1) << 6) + (((((qr & 1) << 2) | g) ^ ((qr >> 1) & 7)) << 3);

  // ---- DMA duty: waves 0,1 -> KB halves; waves 2,3 -> KT halves.
  // Each gl_lds16 writes 1KB (64 lanes x 16B, linear); 8 per wave per tile.
  const f16* wsrc = ws + ((wave >> 1) ? 524288 : 0) + ((wave & 1) << 12) + lane * 8;
  const int dst_half = (wave & 1) << 12;  // f16 offset of this wave's half

  // prologue: stage tile 0 into buffer 0
  {
    f16* dstb = ((wave >> 1) ? &KT[0][0] : &KB[0][0]) + dst_half;
    #pragma unroll
    for (int i = 0; i < 8; ++i) gl_lds16(wsrc + i * 512, dstb + i * 512);
  }
  __syncthreads();

  for (int t = 0; t < NT; ++t) {
    const int cur = t & 1;

    // ---- issue next-tile DMA into other buffer (drained by end barrier)
    if (t + 1 < NT) {
      f16* dstb = ((wave >> 1) ? &KT[cur ^ 1][0] : &KB[cur ^ 1][0]) + dst_half;
      const f16* s = wsrc + (t + 1) * 8192;
      #pragma unroll
      for (int i = 0; i < 8; ++i) gl_lds16(s + i * 512, dstb + i * 512);
    }

    // ---- score: S^T[key'][q], key-permuted A-rows, q exact via hi/lo
    const f16* KBc = &KB[cur][0];
    f32x4 s0 = (f32x4){0.f, 0.f, 0.f, 0.f};
    f32x4 s1 = (f32x4){0.f, 0.f, 0.f, 0.f};
    #pragma unroll
    for (int dt = 0; dt < 8; ++dt) {
      int c = (dt << 2) + g;
      f16x8 a0 = *(const f16x8*)&KBc[rb0 + ((c ^ x0) << 3)];
      f16x8 a1 = *(const f16x8*)&KBc[rb1 + ((c ^ x1) << 3)];
      s0 = MF32(a0, qh[dt], s0); s0 = MF32(a0, ql[dt], s0);
      s1 = MF32(a1, qh[dt], s1); s1 = MF32(a1, ql[dt], s1);
    }
    // lane holds S[q=qr][key 8g+i] (s0) and 8g+4+i (s1)

    // ---- online softmax (row = qr); defer-max (T13)
    float tmax = fmaxf(fmaxf(fmaxf(s0[0], s0[1]), fmaxf(s0[2], s0[3])),
                       fmaxf(fmaxf(s1[0], s1[1]), fmaxf(s1[2], s1[3])));
    tmax = fmaxf(tmax, __shfl_xor(tmax, 16));
    tmax = fmaxf(tmax, __shfl_xor(tmax, 32));

    if (__any(tmax > m_run + 8.f)) {
      float m_new = fmaxf(m_run, tmax);
      float sc = __expf(m_run - m_new);
      l_run *= sc;
      m_run = m_new;
      float osc0 = __shfl(sc, g * 4 + 0);
      float osc1 = __shfl(sc, g * 4 + 1);
      float osc2 = __shfl(sc, g * 4 + 2);
      float osc3 = __shfl(sc, g * 4 + 3);
      #pragma unroll
      for (int dtile = 0; dtile < 16; ++dtile) {
        O[dtile][0] *= osc0; O[dtile][1] *= osc1;
        O[dtile][2] *= osc2; O[dtile][3] *= osc3;
      }
    }

    float ts = 0.f;
    f16x8 pa;  // x32 PV A-frag: k = g*8+j -> phys key 8g+j
    #pragma unroll
    for (int i = 0; i < 4; ++i) {
      float e0 = __expf(s0[i] - m_run);
      float e1 = __expf(s1[i] - m_run);
      ts += e0 + e1;
      pa[i] = (f16)e0;
      pa[4 + i] = (f16)e1;
    }
    ts += __shfl_xor(ts, 16);
    ts += __shfl_xor(ts, 32);
    l_run += ts;

    // ---- PV: all-x32, B-frags from KT image (compile-time strides)
    const f16* KTc = &KT[cur][0];
    #pragma unroll
    for (int dtile = 0; dtile < 16; ++dtile) {
      f16x8 vb = *(const f16x8*)&KTc[dtile * 512 + rbT];
      O[dtile] = MF32(pa, vb, O[dtile]);
    }

    __syncthreads();  // next-tile images complete; buffers swap
  }

  // ---- epilogue: normalize by row-sum, store NCHW (float4 over w)
  float n0 = 1.f / __shfl(l_run, g * 4 + 0);
  float n1 = 1.f / __shfl(l_run, g * 4 + 1);
  float n2 = 1.f / __shfl(l_run, g * 4 + 2);
  float n3 = 1.f / __shfl(l_run, g * 4 + 3);
  float* ob = out + ((size_t)b << 20) + hwbase + wave * 16 + g * 4;
  #pragma unroll
  for (int dtile = 0; dtile < 16; ++dtile) {
    int c = dtile * 16 + qr;
    float4 w4;
    w4.x = O[dtile][0] * n0;
    w4.y = O[dtile][1] * n1;
    w4.z = O[dtile][2] * n2;
    w4.w = O[dtile][3] * n3;
    *(float4*)(ob + ((size_t)c << 12)) = w4;
  }
}

extern "C" void kernel_launch(void* const* d_in, const int* in_sizes, int n_in,
                              void* d_out, int out_size, void* d_ws, size_t ws_size,
                              hipStream_t stream) {
  const float* keys  = (const float*)d_in[0];
  const float* query = (const float*)d_in[1];
  float* out = (float*)d_out;
  f16* ws = (f16*)d_ws;
  hipLaunchKernelGGL(prep_kernel, dim3(256), dim3(256), 0, stream, keys, ws);
  hipLaunchKernelGGL(mtr_kernel, dim3(512), dim3(256), 0, stream, ws, query, out);
}